// Round 4
// baseline (294.636 us; speedup 1.0000x reference)
//
#include <hip/hip_runtime.h>
#include <stdint.h>

typedef __bf16 bf16_t;
typedef __bf16 bf16x8 __attribute__((ext_vector_type(8)));
typedef float f32x4 __attribute__((ext_vector_type(4)));
typedef unsigned short us16x8 __attribute__((ext_vector_type(8)));

#define MFMA16(a, b, c) __builtin_amdgcn_mfma_f32_16x16x32_bf16(a, b, c, 0, 0, 0)
#define BAR() __builtin_amdgcn_s_barrier()
#define PRIO1() __builtin_amdgcn_s_setprio(1)
#define PRIO0() __builtin_amdgcn_s_setprio(0)
#define LGKM0()                                       \
  do {                                                \
    asm volatile("s_waitcnt lgkmcnt(0)" ::: "memory"); \
    __builtin_amdgcn_sched_barrier(0);                \
  } while (0)
#define VMCNT(n)                                             \
  do {                                                       \
    asm volatile("s_waitcnt vmcnt(" #n ")" ::: "memory");    \
    __builtin_amdgcn_sched_barrier(0);                       \
  } while (0)

__device__ __forceinline__ void stage16(const bf16_t* g, bf16_t* l) {
  __builtin_amdgcn_global_load_lds((__attribute__((address_space(1))) void*)g,
                                   (__attribute__((address_space(3))) void*)l, 16, 0, 0);
}

// ---------------- f32 -> bf16 conversion ----------------
__global__ __launch_bounds__(256) void cvt_f32_to_bf16(const float* __restrict__ in,
                                                       bf16_t* __restrict__ out, int n8) {
  int i = blockIdx.x * 256 + threadIdx.x;
  if (i >= n8) return;
  const f32x4* p = (const f32x4*)(in + (size_t)i * 8);
  f32x4 a = p[0], b = p[1];
  bf16x8 o;
  o[0] = (bf16_t)a[0]; o[1] = (bf16_t)a[1]; o[2] = (bf16_t)a[2]; o[3] = (bf16_t)a[3];
  o[4] = (bf16_t)b[0]; o[5] = (bf16_t)b[1]; o[6] = (bf16_t)b[2]; o[7] = (bf16_t)b[3];
  *(bf16x8*)(out + (size_t)i * 8) = o;
}

// ================= 256x256 8-phase NT GEMM (T2+T3+T4+T5) =================
// C[M,N] = A[M,K]*B[N,K]^T + bias, bf16 out. 512 thr = 8 waves (2M x 4N),
// per-wave C = 128x64 (acc[8][4]). BK=64, LDS = 2buf x (A[256][64]+B[256][64]) = 128 KiB.
// Region liveness (reads of current tile): A0/A1 regions read in Ph1 AND Ph3;
// B0/B1 regions read in Ph1 AND Ph2. Therefore same-buffer stages: B0 -> Ph3,
// A0+B1 -> Ph4 (RACE FIX vs r3: A0 was in Ph2, overwriting rows re-read in Ph3).
// Other-buffer stage A1(t+1) -> Ph1. vmcnt(6) at Ph4: newest load of tile t+1
// is A1(t+1) [Ph1]; after it: B0(t+2)+A0(t+2)+B1(t+2) = 6 -> drains tile t+1.
struct G8P {
  const bf16_t* Ab;  // A + (bm*256 + row0)*K + swc0  (per-thread)
  const bf16_t* Bb;
  bf16_t* SA;
  bf16_t* SB;
  int K, nk, tid, ardBase, brdBase, pb0, pb1;
};

__device__ __forceinline__ void stage_half(const bf16_t* src, bf16_t* dst, int K) {
  stage16(src, dst);
  stage16(src + ((size_t)K << 6), dst + 4096);
}

template <int CUR>
__device__ __forceinline__ void g8p_group(const G8P& g, int t, bf16x8 (&aR)[4][2],
                                          bf16x8 (&bR0)[2][2], bf16x8 (&bR1)[2][2],
                                          f32x4 (&acc)[8][4]) {
  const int t1 = (t + 1 < g.nk) ? t + 1 : g.nk - 1;
  const int t2 = (t + 2 < g.nk) ? t + 2 : g.nk - 1;
  bf16_t* SAc = g.SA + CUR * 16384;
  bf16_t* SBc = g.SB + CUR * 16384;
  bf16_t* SAn = g.SA + (1 - CUR) * 16384;

  // ---- Phase 1: read A-lo,B0 subtiles; stage A1(t+1) -> other buf ----
#pragma unroll
  for (int mi = 0; mi < 4; ++mi) {
    aR[mi][0] = *(const bf16x8*)(SAc + g.ardBase + mi * 1024 + g.pb0);
    aR[mi][1] = *(const bf16x8*)(SAc + g.ardBase + mi * 1024 + g.pb1);
  }
#pragma unroll
  for (int ni = 0; ni < 2; ++ni) {
    bR0[ni][0] = *(const bf16x8*)(SBc + g.brdBase + ni * 1024 + g.pb0);
    bR0[ni][1] = *(const bf16x8*)(SBc + g.brdBase + ni * 1024 + g.pb1);
  }
  stage_half(g.Ab + (size_t)128 * g.K + (size_t)t1 * 64, SAn + 8192 + g.tid * 8, g.K);
  BAR();
  LGKM0();
  PRIO1();
#pragma unroll
  for (int mi = 0; mi < 4; ++mi)
#pragma unroll
    for (int ni = 0; ni < 2; ++ni) {
      acc[mi][ni] = MFMA16(aR[mi][0], bR0[ni][0], acc[mi][ni]);
      acc[mi][ni] = MFMA16(aR[mi][1], bR0[ni][1], acc[mi][ni]);
    }
  PRIO0();
  BAR();

  // ---- Phase 2: read B1 subtiles (no staging — B1 region still read here) ----
#pragma unroll
  for (int ni = 0; ni < 2; ++ni) {
    bR1[ni][0] = *(const bf16x8*)(SBc + g.brdBase + (2 + ni) * 1024 + g.pb0);
    bR1[ni][1] = *(const bf16x8*)(SBc + g.brdBase + (2 + ni) * 1024 + g.pb1);
  }
  BAR();
  LGKM0();
  PRIO1();
#pragma unroll
  for (int mi = 0; mi < 4; ++mi)
#pragma unroll
    for (int ni = 0; ni < 2; ++ni) {
      acc[mi][2 + ni] = MFMA16(aR[mi][0], bR1[ni][0], acc[mi][2 + ni]);
      acc[mi][2 + ni] = MFMA16(aR[mi][1], bR1[ni][1], acc[mi][2 + ni]);
    }
  PRIO0();
  BAR();

  // ---- Phase 3: read A-hi subtiles (overwrite aR); stage B0(t+2) -> this buf ----
#pragma unroll
  for (int mi = 0; mi < 4; ++mi) {
    aR[mi][0] = *(const bf16x8*)(SAc + g.ardBase + (4 + mi) * 1024 + g.pb0);
    aR[mi][1] = *(const bf16x8*)(SAc + g.ardBase + (4 + mi) * 1024 + g.pb1);
  }
  stage_half(g.Bb + (size_t)t2 * 64, SBc + g.tid * 8, g.K);
  BAR();
  LGKM0();
  PRIO1();
#pragma unroll
  for (int mi = 0; mi < 4; ++mi)
#pragma unroll
    for (int ni = 0; ni < 2; ++ni) {
      acc[4 + mi][2 + ni] = MFMA16(aR[mi][0], bR1[ni][0], acc[4 + mi][2 + ni]);
      acc[4 + mi][2 + ni] = MFMA16(aR[mi][1], bR1[ni][1], acc[4 + mi][2 + ni]);
    }
  PRIO0();
  BAR();

  // ---- Phase 4: stage A0(t+2) + B1(t+2) (A-lo dead after Ph3's reload);
  //      counted vmcnt(6) -> tile t+1 landed, 3 half-tiles stay in flight ----
  stage_half(g.Ab + (size_t)t2 * 64, SAc + g.tid * 8, g.K);
  stage_half(g.Bb + (size_t)128 * g.K + (size_t)t2 * 64, SBc + 8192 + g.tid * 8, g.K);
  VMCNT(6);
  BAR();
  PRIO1();
#pragma unroll
  for (int mi = 0; mi < 4; ++mi)
#pragma unroll
    for (int ni = 0; ni < 2; ++ni) {
      acc[4 + mi][ni] = MFMA16(aR[mi][0], bR0[ni][0], acc[4 + mi][ni]);
      acc[4 + mi][ni] = MFMA16(aR[mi][1], bR0[ni][1], acc[4 + mi][ni]);
    }
  PRIO0();
  BAR();
}

__global__ __launch_bounds__(512, 2) void gemm_nt_8p(const bf16_t* __restrict__ A,
                                                     const bf16_t* __restrict__ B,
                                                     const float* __restrict__ bias,
                                                     bf16_t* __restrict__ C,
                                                     int M, int N, int K) {
  __shared__ bf16_t SA[2 * 256 * 64];
  __shared__ bf16_t SB[2 * 256 * 64];
  int tid = threadIdx.x;
  int l = tid & 63, w = tid >> 6;
  int l15 = l & 15, l4 = l >> 4, l7 = l & 7;
  int wm = w >> 2, wn = w & 3;
  int nbn = N >> 8;
  // XCD-aware bijective swizzle (grid % 8 == 0)
  int nwg = gridDim.x;
  int bid = blockIdx.x;
  int wg = (bid & 7) * (nwg >> 3) + (bid >> 3);
  int bm = wg / nbn, bn = wg % nbn;

  // per-thread staging source base: row0 = tid>>3 (0..63), pre-swizzled col
  int row0 = tid >> 3;
  int swc0 = ((tid & 7) ^ (row0 & 7)) << 3;
  G8P g;
  g.Ab = A + (size_t)(bm * 256 + row0) * K + swc0;
  g.Bb = B + (size_t)(bn * 256 + row0) * K + swc0;
  g.SA = SA; g.SB = SB;
  g.K = K; g.nk = K >> 6; g.tid = tid;
  g.ardBase = (wm * 128 + l15) * 64;
  g.brdBase = (wn * 64 + l15) * 64;
  g.pb0 = ((l4) ^ l7) << 3;
  g.pb1 = ((4 + l4) ^ l7) << 3;

  f32x4 acc[8][4] = {};
  bf16x8 aR[4][2], bR0[2][2], bR1[2][2];

  // ---- prologue: t0 fully (A0,B0,B1,A1) then t1's A0,B0,B1; vmcnt(6) = t0 landed ----
  {
    int t1 = (g.nk > 1) ? 1 : 0;
    stage_half(g.Ab, SA + tid * 8, K);                                        // A0(0)
    stage_half(g.Bb, SB + tid * 8, K);                                        // B0(0)
    stage_half(g.Bb + (size_t)128 * K, SB + 8192 + tid * 8, K);               // B1(0)
    stage_half(g.Ab + (size_t)128 * K, SA + 8192 + tid * 8, K);               // A1(0)
    stage_half(g.Ab + (size_t)t1 * 64, SA + 16384 + tid * 8, K);              // A0(1)
    stage_half(g.Bb + (size_t)t1 * 64, SB + 16384 + tid * 8, K);              // B0(1)
    stage_half(g.Bb + (size_t)128 * K + (size_t)t1 * 64, SB + 16384 + 8192 + tid * 8, K);  // B1(1)
    VMCNT(6);
    BAR();
  }

  for (int t = 0; t < g.nk; t += 2) {
    g8p_group<0>(g, t, aR, bR0, bR1, acc);
    g8p_group<1>(g, t + 1, aR, bR0, bR1, acc);
  }
  asm volatile("s_waitcnt vmcnt(0)" ::: "memory");

  // ---- epilogue ----
  int rbase = bm * 256 + wm * 128 + (l4 << 2);
  int cbase = bn * 256 + wn * 64 + l15;
#pragma unroll
  for (int ni = 0; ni < 4; ++ni) {
    float bv = bias[cbase + ni * 16];
#pragma unroll
    for (int mi = 0; mi < 8; ++mi)
#pragma unroll
      for (int r = 0; r < 4; ++r) {
        size_t off = (size_t)(rbase + mi * 16 + r) * N + (cbase + ni * 16);
        C[off] = (bf16_t)(acc[mi][ni][r] + bv);
      }
  }
}

// ---------------- NT GEMM: 128x128 2-barrier (kept for GEMM2: grid=512 blocks) ----
template <int OUT_BF16>
__global__ __launch_bounds__(256) void gemm_nt(const bf16_t* __restrict__ A,
                                               const bf16_t* __restrict__ B,
                                               const float* __restrict__ bias,
                                               void* __restrict__ Cout,
                                               int M, int N, int K) {
  __shared__ bf16_t As[128 * 64];
  __shared__ bf16_t Bs[128 * 64];
  int tid = threadIdx.x;
  int l = tid & 63, w = tid >> 6;
  int wr = w >> 1, wc = w & 1;
  int nbn = N >> 7;
  int bm = blockIdx.x / nbn, bn = blockIdx.x % nbn;
  int l15 = l & 15, l4 = l >> 4, l7 = l & 7;

  f32x4 acc[4][4] = {};

  for (int ks = 0; ks < K; ks += 64) {
#pragma unroll
    for (int i = 0; i < 4; ++i) {
      int e = i * 256 + tid;
      int row = e >> 3, blk = e & 7;
      int col = ks + ((blk ^ (row & 7)) << 3);
      stage16(A + (size_t)(bm * 128 + row) * K + col, As + e * 8);
      stage16(B + (size_t)(bn * 128 + row) * K + col, Bs + e * 8);
    }
    __syncthreads();
#pragma unroll
    for (int kk = 0; kk < 2; ++kk) {
      bf16x8 af[4], bfr[4];
      int blk = (kk * 4 + l4) ^ l7;
#pragma unroll
      for (int m = 0; m < 4; ++m) {
        af[m] = *(const bf16x8*)(As + (wr * 64 + m * 16 + l15) * 64 + blk * 8);
        bfr[m] = *(const bf16x8*)(Bs + (wc * 64 + m * 16 + l15) * 64 + blk * 8);
      }
#pragma unroll
      for (int m = 0; m < 4; ++m)
#pragma unroll
        for (int n = 0; n < 4; ++n)
          acc[m][n] = MFMA16(af[m], bfr[n], acc[m][n]);
    }
    __syncthreads();
  }

  int rbase = bm * 128 + wr * 64 + (l4 << 2);
  int cbase = bn * 128 + wc * 64 + l15;
#pragma unroll
  for (int n = 0; n < 4; ++n) {
    float bv = bias[cbase + n * 16];
#pragma unroll
    for (int m = 0; m < 4; ++m)
#pragma unroll
      for (int r = 0; r < 4; ++r) {
        float v = acc[m][n][r] + bv;
        size_t off = (size_t)(rbase + m * 16 + r) * N + (cbase + n * 16);
        if (OUT_BF16) ((bf16_t*)Cout)[off] = (bf16_t)v;
        else ((float*)Cout)[off] = v;
      }
  }
}

// ---------------- causal flash attention (unchanged) ----------------
__global__ __launch_bounds__(256, 2) void attn_fwd(const bf16_t* __restrict__ qkv,
                                                   bf16_t* __restrict__ att) {
  __shared__ bf16_t Kt[64 * 128];
  __shared__ bf16_t Vt[128 * 64];
  __shared__ bf16_t Pw[4][16 * 64];

  int bid = blockIdx.x;
  int pair = bid >> 5, bh = bid & 31;
  int h = bh & 15, b = bh >> 4;
  int tid = threadIdx.x;
  int l = tid & 63, w = tid >> 6;
  int l15 = l & 15, l4 = l >> 4, l7 = l & 7;
  const size_t LD = 6144;
  const bf16_t* base = qkv + (size_t)b * 2048 * LD;

#pragma unroll 1
  for (int phase = 0; phase < 2; ++phase) {
    int qt = phase ? 31 - pair : pair;
    int q0 = qt << 6;
    int wq0 = q0 + w * 16;

    bf16x8 qf[4];
#pragma unroll
    for (int kk = 0; kk < 4; ++kk)
      qf[kk] = *(const bf16x8*)(base + (size_t)(wq0 + l15) * LD + h * 128 + kk * 32 + l4 * 8);

    f32x4 acc[8] = {};
    float mrow[4], lrow[4];
#pragma unroll
    for (int r = 0; r < 4; ++r) { mrow[r] = -1e30f; lrow[r] = 0.f; }

    int nkt = qt + 1;
    for (int kt = 0; kt < nkt; ++kt) {
      int kb = kt << 6;
      const bf16_t* vg = base + (size_t)kb * LD + 4096 + h * 128;
      us16x8 va[2], vb[2];
#pragma unroll
      for (int p = 0; p < 2; ++p) {
        int g = p * 256 + tid;
        int kv = (g >> 4) << 1;
        int d0 = (g & 15) << 3;
        va[p] = *(const us16x8*)(vg + (size_t)kv * LD + d0);
        vb[p] = *(const us16x8*)(vg + (size_t)(kv + 1) * LD + d0);
      }
      const bf16_t* kg = base + (size_t)kb * LD + 2048 + h * 128;
#pragma unroll
      for (int i = 0; i < 4; ++i) {
        int e = i * 256 + tid;
        int row = e >> 4, blk = e & 15;
        int src = (blk ^ (row & 7)) << 3;
        stage16(kg + (size_t)row * LD + src, Kt + e * 8);
      }
#pragma unroll
      for (int p = 0; p < 2; ++p) {
        int g = p * 256 + tid;
        int kv = (g >> 4) << 1;
        int d0 = (g & 15) << 3;
        int k8 = kv >> 3, kr = kv & 7;
#pragma unroll
        for (int j = 0; j < 8; ++j) {
          int d = d0 + j;
          int swz = k8 ^ ((d ^ (d >> 3)) & 7);
          unsigned pack = (unsigned)va[p][j] | ((unsigned)vb[p][j] << 16);
          *(unsigned*)(&Vt[d * 64 + swz * 8 + kr]) = pack;
        }
      }
      __syncthreads();

      {
        f32x4 s[4] = {};
        __builtin_amdgcn_s_setprio(1);
#pragma unroll
        for (int kk = 0; kk < 4; ++kk) {
          int blk = (kk * 4 + l4) ^ l7;
#pragma unroll
          for (int n = 0; n < 4; ++n) {
            bf16x8 kf = *(const bf16x8*)(Kt + (n * 16 + l15) * 128 + blk * 8);
            s[n] = MFMA16(qf[kk], kf, s[n]);
          }
        }
        __builtin_amdgcn_s_setprio(0);

        const float sc = 0.08838834764831845f;
        bool needMask = (kb + 63) > wq0;
        float scf[4];
#pragma unroll
        for (int r = 0; r < 4; ++r) {
          int q = wq0 + (l4 << 2) + r;
#pragma unroll
          for (int n = 0; n < 4; ++n) {
            float v = s[n][r] * sc;
            if (needMask && (kb + n * 16 + l15) > q) v = -1e30f;
            s[n][r] = v;
          }
          float mx = fmaxf(fmaxf(s[0][r], s[1][r]), fmaxf(s[2][r], s[3][r]));
          mx = fmaxf(mx, __shfl_xor(mx, 1));
          mx = fmaxf(mx, __shfl_xor(mx, 2));
          mx = fmaxf(mx, __shfl_xor(mx, 4));
          mx = fmaxf(mx, __shfl_xor(mx, 8));
          float mn = fmaxf(mrow[r], mx);
          float sf = __expf(mrow[r] - mn);
          mrow[r] = mn;
          scf[r] = sf;
          float rs = 0.f;
#pragma unroll
          for (int n = 0; n < 4; ++n) {
            float pv = __expf(s[n][r] - mn);
            s[n][r] = pv;
            rs += pv;
          }
          rs += __shfl_xor(rs, 1);
          rs += __shfl_xor(rs, 2);
          rs += __shfl_xor(rs, 4);
          rs += __shfl_xor(rs, 8);
          lrow[r] = lrow[r] * sf + rs;
        }
#pragma unroll
        for (int nd = 0; nd < 8; ++nd)
#pragma unroll
          for (int r = 0; r < 4; ++r)
            acc[nd][r] *= scf[r];
#pragma unroll
        for (int n = 0; n < 4; ++n) {
          int cb8 = n * 2 + (l15 >> 3);
#pragma unroll
          for (int r = 0; r < 4; ++r) {
            int row = (l4 << 2) + r;
            Pw[w][row * 64 + ((cb8 ^ (row & 7)) << 3) + l7] = (bf16_t)s[n][r];
          }
        }
        __builtin_amdgcn_s_setprio(1);
#pragma unroll
        for (int kk2 = 0; kk2 < 2; ++kk2) {
          bf16x8 pa = *(const bf16x8*)(&Pw[w][l15 * 64 + (((kk2 * 4 + l4) ^ l7) << 3)]);
#pragma unroll
          for (int nd = 0; nd < 8; ++nd) {
            int d = nd * 16 + l15;
            int swz = (kk2 * 4 + l4) ^ ((d ^ (d >> 3)) & 7);
            bf16x8 bv = *(const bf16x8*)(&Vt[d * 64 + swz * 8]);
            acc[nd] = MFMA16(pa, bv, acc[nd]);
          }
        }
        __builtin_amdgcn_s_setprio(0);
      }
      __syncthreads();
    }

#pragma unroll
    for (int r = 0; r < 4; ++r) {
      float inv = 1.0f / lrow[r];
      size_t ro = (size_t)(b * 2048 + wq0 + (l4 << 2) + r) * 2048 + h * 128;
#pragma unroll
      for (int nd = 0; nd < 8; ++nd)
        att[ro + nd * 16 + l15] = (bf16_t)(acc[nd][r] * inv);
    }
  }
}

// ---------------- launch ----------------
extern "C" void kernel_launch(void* const* d_in, const int* in_sizes, int n_in,
                              void* d_out, int out_size, void* d_ws, size_t ws_size,
                              hipStream_t stream) {
  (void)in_sizes; (void)n_in; (void)out_size; (void)ws_size;
  const float* x = (const float*)d_in[0];
  const float* w_attn = (const float*)d_in[1];
  const float* b_attn = (const float*)d_in[2];
  const float* w_proj = (const float*)d_in[3];
  const float* b_proj = (const float*)d_in[4];
  float* out = (float*)d_out;

  char* ws = (char*)d_ws;
  bf16_t* xb  = (bf16_t*)(ws);
  bf16_t* wab = (bf16_t*)(ws + 16777216);
  bf16_t* wpb = (bf16_t*)(ws + 41943040);
  bf16_t* qkv = (bf16_t*)(ws + 50331648);
  bf16_t* att = xb;  // xb dead after GEMM1

  cvt_f32_to_bf16<<<4096, 256, 0, stream>>>(x, xb, 1048576);
  cvt_f32_to_bf16<<<6144, 256, 0, stream>>>(w_attn, wab, 1572864);
  cvt_f32_to_bf16<<<2048, 256, 0, stream>>>(w_proj, wpb, 524288);

  // qkv = x @ w_attn^T + b_attn -> bf16 [4096, 6144]  (8-phase 256^2, 16x24=384 blocks)
  gemm_nt_8p<<<384, 512, 0, stream>>>(xb, wab, b_attn, qkv, 4096, 6144, 2048);

  // causal flash attention -> att bf16 [4096, 2048]
  attn_fwd<<<512, 256, 0, stream>>>(qkv, att);

  // out = att @ w_proj^T + b_proj -> f32 [4096, 2048]  (128^2, 512 blocks)
  gemm_nt<0><<<32 * 16, 256, 0, stream>>>(att, wpb, b_proj, out, 4096, 2048, 2048);
}